// Round 10
// baseline (110.851 us; speedup 1.0000x reference)
//
#include <hip/hip_runtime.h>

// GraphAutoEncoder, SINGLE kernel, EIGHT threads per graph (B=131072, N=8).
// Block = 512 threads = 8 waves; wave w = role w; lane L = graph g of block.
// Role split: encoder 1 node, Gabriel 4-or-3 pairs, n/cj 1 row+1 col, GCN1 4
// features, pooled 4 g's, decoder 8 h's. 6 barriers, 16 KB phase-aliased LDS.
// __launch_bounds__(512,8): VGPR<=64, 4 blocks/CU = 32 waves/CU (cap).
// vs r9 (4-role, 106.06): per-thread serial chain halved (~2200 -> ~1160 sc
// insts); all decision + per-stage accumulation arithmetic bit-identical;
// only the final 64-h partial-sum tree is 8-way instead of 4-way.
// LDS arena windows (floats), all aliases barrier-separated:
//   [0,1024)    p[8][64]v2   -> t rows 0..7   -> o[8][64] in [0,512)
//   [1024,2048) masks[8][2][64]u32 -> t rows 8..15
//   [2048,3072) n[8][64]v2   -> pooled rows 0..15
//   [3072,3584) cj[8][64]    -> pooled rows 16..23
//   [3584,4096) (pooled rows 24..31)

typedef float v2 __attribute__((ext_vector_type(2)));
static __device__ __forceinline__ v2 sp(float s) { return (v2){s, s}; }
static __device__ __forceinline__ v2 fma2(v2 a, v2 b, v2 c) {
    return __builtin_elementwise_fma(a, b, c);
}
static __device__ __forceinline__ v2 ldv2(const float* p) {
    return *reinterpret_cast<const v2*>(p);
}

// Gabriel pair test, both directions. Op order identical to rounds 2-9.
template <int I, int J>
static __device__ __forceinline__ void gpair(const v2* __restrict__ p,
                                             unsigned& ml, unsigned& mh)
{
    #pragma clang fp contract(off)
    v2 mid = (p[I] + p[J]) * sp(0.5f);
    v2 di = p[I] - mid;  v2 si = di * di;  float r2i = si.x + si.y;
    v2 dj = p[J] - mid;  v2 sj = dj * dj;  float r2j = sj.x + sj.y;
    float dmin = 3.4e38f;
    #pragma unroll
    for (int k = 0; k < 8; ++k) {
        if (k == I || k == J) continue;
        v2 dk = p[k] - mid;
        v2 sk = dk * dk;
        dmin = fminf(dmin, sk.x + sk.y);
    }
    constexpr unsigned bi = 1u << (((I & 3) * 8) + J);  // row I, bit J
    constexpr unsigned bj = 1u << (((J & 3) * 8) + I);  // row J, bit I
    if (I < 4) ml |= (dmin < r2i) ? 0u : bi; else mh |= (dmin < r2i) ? 0u : bi;
    if (J < 4) ml |= (dmin < r2j) ? 0u : bj; else mh |= (dmin < r2j) ? 0u : bj;
}

__global__ __launch_bounds__(512, 8) void gae_main(
    const float* __restrict__ x,        // (B,8)
    const float* __restrict__ enc_w1,   // (3,64)
    const float* __restrict__ enc_b1,   // (64,)
    const float* __restrict__ enc_w2,   // (64,2)
    const float* __restrict__ enc_b2,   // (2,)
    const float* __restrict__ gcn1_w,   // (2,32)
    const float* __restrict__ gcn1_b,   // (32,)
    const float* __restrict__ gcn2_w,   // (32,32)
    const float* __restrict__ gcn2_b,   // (32,)
    const float* __restrict__ dec_w1,   // (32,64)
    const float* __restrict__ dec_b1,   // (64,)
    const float* __restrict__ dec_w2,   // (64,3)
    const float* __restrict__ dec_b2,   // (3,)
    float* __restrict__ out_rec,        // (B,8)
    float* __restrict__ out_lat,        // (B,8,2)
    int B)
{
    __shared__ __align__(16) float smem[4096];            // 16 KB arena
    v2*       const P2 = reinterpret_cast<v2*>(smem);               // p rows
    unsigned* const MB = reinterpret_cast<unsigned*>(smem + 1024);  // masks
    v2*       const N2 = reinterpret_cast<v2*>(smem + 2048);        // n rows
    float*    const CJ = smem + 3072;                               // cj rows
    v2*       const T2 = reinterpret_cast<v2*>(smem);               // t rows
    float*    const PL = smem + 2048;                               // pooled
    float*    const OO = smem;                                      // o parts

    const int lane = threadIdx.x & 63;
    const int ru   = __builtin_amdgcn_readfirstlane(threadIdx.x >> 6); // 0..7
    int g = blockIdx.x * 64 + lane;
    if (g >= B) g = B - 1;

    // ---- load own node's x (4B/lane) ----
    const float xi = x[(size_t)g * 8 + ru];
    const float ifl = (float)ru;

    // ---- encoder, own node (node ru); bit-identical per-node math ----
    v2 pl = ldv2(enc_b2);
    #pragma unroll 8
    for (int h = 0; h < 64; ++h) {
        const float wx = enc_w1[64 + h];
        const float wi = enc_w1[128 + h];
        const float bb = enc_b1[h];
        const v2 uxy = ldv2(enc_w2 + 2 * h);
        float t = fmaf(xi, wx, fmaf(ifl, wi, bb));
        t = fmaxf(t, 0.0f);
        pl = fma2(sp(t), uxy, pl);
    }
    // (global latent store deferred to kernel end)

    // ---- exchange latent ----
    P2[ru * 64 + lane] = pl;
    __syncthreads();                                      // barrier 1
    v2 p[8];
    #pragma unroll
    for (int j = 0; j < 8; ++j) p[j] = P2[j * 64 + lane];

    // ---- Gabriel, 4-or-3 pairs per role ----
    unsigned ml = 0u, mh = 0u;
    if      (ru == 0) { gpair<0,1>(p, ml, mh); gpair<0,2>(p, ml, mh);
                        gpair<0,3>(p, ml, mh); gpair<0,4>(p, ml, mh); }
    else if (ru == 1) { gpair<0,5>(p, ml, mh); gpair<0,6>(p, ml, mh);
                        gpair<0,7>(p, ml, mh); gpair<1,2>(p, ml, mh); }
    else if (ru == 2) { gpair<1,3>(p, ml, mh); gpair<1,4>(p, ml, mh);
                        gpair<1,5>(p, ml, mh); gpair<1,6>(p, ml, mh); }
    else if (ru == 3) { gpair<1,7>(p, ml, mh); gpair<2,3>(p, ml, mh);
                        gpair<2,4>(p, ml, mh); gpair<2,5>(p, ml, mh); }
    else if (ru == 4) { gpair<2,6>(p, ml, mh); gpair<2,7>(p, ml, mh);
                        gpair<3,4>(p, ml, mh); }
    else if (ru == 5) { gpair<3,5>(p, ml, mh); gpair<3,6>(p, ml, mh);
                        gpair<3,7>(p, ml, mh); }
    else if (ru == 6) { gpair<4,5>(p, ml, mh); gpair<4,6>(p, ml, mh);
                        gpair<4,7>(p, ml, mh); }
    else              { gpair<5,6>(p, ml, mh); gpair<5,7>(p, ml, mh);
                        gpair<6,7>(p, ml, mh); }

    // ---- combine masks (+ self loops) ----
    MB[ru * 128 +  0 + lane] = ml;
    MB[ru * 128 + 64 + lane] = mh;
    __syncthreads();                                      // barrier 2
    {
        unsigned al = 0u, ah = 0u;
        #pragma unroll
        for (int r = 0; r < 8; ++r) {
            al |= MB[r * 128 + lane];
            ah |= MB[r * 128 + 64 + lane];
        }
        ml = al | 0x08040201u;
        mh = ah | 0x80402010u;
    }

    // ---- dinv[8], q[8] (compile-time indexed -> registers) ----
    float dinv[8];
    v2 q[8];
    #pragma unroll
    for (int i = 0; i < 8; ++i) {
        const unsigned rb = ((i < 4 ? ml : mh) >> ((i & 3) * 8)) & 0xffu;
        dinv[i] = __builtin_amdgcn_rsqf((float)__popc(rb));
        q[i] = sp(dinv[i]) * p[i];
    }

    // ---- own 1 row of n, own 1 col of cj; publish to LDS ----
    {
        const unsigned w = (ru < 4) ? ml : mh;
        const unsigned rb = (w >> ((ru & 3) * 8)) & 0xffu;
        const float dv = __builtin_amdgcn_rsqf((float)__popc(rb));
        v2 a = sp(0.0f);
        #pragma unroll
        for (int j = 0; j < 8; ++j)
            a = fma2(sp((float)((rb >> j) & 1u)), q[j], a);
        N2[ru * 64 + lane] = sp(dv) * a;

        float s = 0.0f;
        #pragma unroll
        for (int i = 0; i < 8; ++i) {
            const unsigned ri = ((i < 4 ? ml : mh) >> ((i & 3) * 8)) & 0xffu;
            s = fmaf((float)((ri >> ru) & 1u), dinv[i], s);
        }
        CJ[ru * 64 + lane] = 0.125f * dv * s;
    }
    __syncthreads();                                      // barrier 3

    // ---- GCN1 + pooled projection, own 4 features (f in [4ru,4ru+4)) ----
    const float* w0 = gcn1_w + 4 * ru;
    const float* w1 = gcn1_w + 32 + 4 * ru;
    const float* bl = gcn1_b + 4 * ru;
    v2 t2[2];
    t2[0] = sp(0.0f); t2[1] = sp(0.0f);
    #pragma unroll
    for (int i = 0; i < 8; ++i) {
        const v2 ni = N2[i * 64 + lane];
        const float ci = CJ[i * 64 + lane];
        const v2 nxi = sp(ni.x), nyi = sp(ni.y), civ = sp(ci);
        #pragma unroll
        for (int fp = 0; fp < 2; ++fp) {
            v2 h = fma2(nxi, ldv2(w0 + 2 * fp),
                   fma2(nyi, ldv2(w1 + 2 * fp), ldv2(bl + 2 * fp)));
            h = __builtin_elementwise_max(h, sp(0.0f));
            t2[fp] = fma2(civ, h, t2[fp]);
        }
    }

    // ---- exchange t (rows 2ru, 2ru+1; overlays dead p + masks regions) ----
    T2[(2 * ru + 0) * 64 + lane] = t2[0];
    T2[(2 * ru + 1) * 64 + lane] = t2[1];
    __syncthreads();                                      // barrier 4

    // ---- pooled, own 4 g's (g in [4ru,4ru+4)): sequential f accumulation ----
    v2 pg2[2];
    pg2[0] = ldv2(gcn2_b + 4 * ru);
    pg2[1] = ldv2(gcn2_b + 4 * ru + 2);
    #pragma unroll
    for (int fp = 0; fp < 16; ++fp) {
        const v2 tv = T2[fp * 64 + lane];                 // ds_read_b64
        #pragma unroll
        for (int half = 0; half < 2; ++half) {
            const int f = 2 * fp + half;
            const v2 tf = sp(half ? tv.y : tv.x);
            const float* wr = gcn2_w + f * 32 + 4 * ru;
            pg2[0] = fma2(tf, ldv2(wr + 0), pg2[0]);
            pg2[1] = fma2(tf, ldv2(wr + 2), pg2[1]);
        }
    }
    // publish pooled rows (overlays dead n/cj region)
    PL[(4 * ru + 0) * 64 + lane] = pg2[0].x;
    PL[(4 * ru + 1) * 64 + lane] = pg2[0].y;
    PL[(4 * ru + 2) * 64 + lane] = pg2[1].x;
    PL[(4 * ru + 3) * 64 + lane] = pg2[1].y;
    __syncthreads();                                      // barrier 5

    // ---- decoder, own 8 h's (h in [8ru,8ru+8)) ----
    const float* db = dec_b1 + 8 * ru;
    v2 a2[4];
    #pragma unroll
    for (int hp = 0; hp < 4; ++hp) a2[hp] = ldv2(db + 2 * hp);
    __builtin_amdgcn_s_setprio(1);
    #pragma unroll
    for (int f = 0; f < 32; ++f) {
        const v2 pfv = sp(PL[f * 64 + lane]);             // ds_read_b32
        const float* wr = dec_w1 + f * 64 + 8 * ru;
        #pragma unroll
        for (int hp = 0; hp < 4; ++hp)
            a2[hp] = fma2(pfv, ldv2(wr + 2 * hp), a2[hp]);
    }
    __builtin_amdgcn_s_setprio(0);
    v2 oacc = sp(0.0f);
    #pragma unroll
    for (int hp = 0; hp < 4; ++hp) {
        v2 rr = __builtin_elementwise_max(a2[hp], sp(0.0f));
        const int h0 = 8 * ru + 2 * hp;
        const v2 wv = (v2){dec_w2[h0 * 3 + 1], dec_w2[h0 * 3 + 4]};
        oacc = fma2(rr, wv, oacc);
    }
    const float opart = oacc.x + oacc.y;

    // ---- combine 8 partials (fixed tree, same on all roles) ----
    OO[ru * 64 + lane] = opart;       // [0,512): t rows 0..3, dead since bar5
    __syncthreads();                                      // barrier 6
    const float outv =
        (((OO[0 * 64 + lane] + OO[1 * 64 + lane]) +
          (OO[2 * 64 + lane] + OO[3 * 64 + lane])) +
         ((OO[4 * 64 + lane] + OO[5 * 64 + lane]) +
          (OO[6 * 64 + lane] + OO[7 * 64 + lane]))) + dec_b2[1];

    // ---- all global stores at the end ----
    *reinterpret_cast<float2*>(out_lat + (size_t)g * 16 + 2 * ru) =
        make_float2(pl.x, pl.y);
    out_rec[(size_t)g * 8 + ru] = outv;
}

extern "C" void kernel_launch(void* const* d_in, const int* in_sizes, int n_in,
                              void* d_out, int out_size, void* d_ws, size_t ws_size,
                              hipStream_t stream) {
    const float* x       = (const float*)d_in[0];
    const float* enc_w1  = (const float*)d_in[1];
    const float* enc_b1  = (const float*)d_in[2];
    const float* enc_w2  = (const float*)d_in[3];
    const float* enc_b2  = (const float*)d_in[4];
    const float* gcn1_w  = (const float*)d_in[5];
    const float* gcn1_b  = (const float*)d_in[6];
    const float* gcn2_w  = (const float*)d_in[7];
    const float* gcn2_b  = (const float*)d_in[8];
    const float* dec_w1  = (const float*)d_in[9];
    const float* dec_b1  = (const float*)d_in[10];
    const float* dec_w2  = (const float*)d_in[11];
    const float* dec_b2  = (const float*)d_in[12];

    const int B = in_sizes[0] / 8;
    float* out_rec = (float*)d_out;                 // (B,8)
    float* out_lat = out_rec + (size_t)B * 8;       // (B,8,2)
    (void)d_ws; (void)ws_size;                      // workspace unused

    const int blocks = (B + 63) / 64;               // 64 graphs per block
    gae_main<<<blocks, 512, 0, stream>>>(
        x, enc_w1, enc_b1, enc_w2, enc_b2,
        gcn1_w, gcn1_b, gcn2_w, gcn2_b,
        dec_w1, dec_b1, dec_w2, dec_b2,
        out_rec, out_lat, B);
}